// Round 14
// baseline (149.407 us; speedup 1.0000x reference)
//
#include <hip/hip_runtime.h>
#include <stdint.h>

// B=8, S=2048, F=512, D=128, C=1000. I/O fp32; internal bf16 MFMA, fp32 accum.
// mean-attention: w[k] = sum_s exp(S[s,k]-10)/l[s]; out_sum = w.V row-major.
// R13 post-mortem: wv-fusion hurt (+4.9us, attn_wv 47us serial tail + 16x V
// re-read). Reverted. R13 profile: attn kernels MfmaUtil 6%, VALU 19%, HBM
// 10%, Occupancy 22% -> latency-bound at 4 blocks/CU (grid- AND LDS-capped).
// R14: occupancy attack. KC 8->16 (grid 2048 = 8 blk/CU) + KV-tile 64->32
// (LDS ~19KB -> 8 blk/CU allowed) = ~2x resident waves for latency hiding.
// Same MFMA totals, same barrier count. qkv_mega/wv/final = R12 verbatim.
#define NB 8
#define SS 2048
#define FF 512
#define DD 128
#define CC 1000
#define KC 16             // KV split factor
#define CHUNK (SS / KC)   // 128
#define KTILE 32          // KV rows per stage

typedef __attribute__((ext_vector_type(8))) short bf16x8;
typedef __attribute__((ext_vector_type(4))) float f32x4;
typedef __attribute__((ext_vector_type(4))) unsigned int u32x4;

__device__ __forceinline__ short f2bf(float f) {
    uint32_t u;
    __builtin_memcpy(&u, &f, 4);
    u = (u + 0x7fffu + ((u >> 16) & 1u)) >> 16;   // RNE
    return (short)u;
}
__device__ __forceinline__ float bf2f(short h) {
    uint32_t u = ((uint32_t)(uint16_t)h) << 16;
    float f;
    __builtin_memcpy(&f, &u, 4);
    return f;
}
// 2x f32 -> packed bf16x2 (lo=a, hi=b), single HW instr (RNE)
__device__ __forceinline__ uint32_t cvtpk(float a, float b) {
    uint32_t r;
    asm("v_cvt_pk_bf16_f32 %0, %1, %2" : "=v"(r) : "v"(a), "v"(b));
    return r;
}
// async 16B global->LDS; LDS dest = wave-uniform base + lane*16
__device__ __forceinline__ void async16(const void* g, void* l) {
    __builtin_amdgcn_global_load_lds(
        (const __attribute__((address_space(1))) uint32_t*)g,
        (__attribute__((address_space(3))) uint32_t*)l, 16, 0, 0);
}

// ---------------------------------------------------------------------------
// Kernel 0 (prep): transpose+cast W [F][D]f32 x3 -> Wt[384][512] bf16
// (row = global output col: mat*128 + d). grid = 768 blocks.
// ---------------------------------------------------------------------------
__global__ void prep(const float* __restrict__ Wq, const float* __restrict__ Wk,
                     const float* __restrict__ Wv, short* __restrict__ Wt)
{
    int id = blockIdx.x * 256 + threadIdx.x;      // 0..196607
    int w = id >> 16, rem = id & 65535;
    int n = rem >> 9, kx = rem & 511;
    const float* Wsrc = (w == 0) ? Wq : (w == 1) ? Wk : Wv;
    Wt[w * 65536 + n * 512 + kx] = f2bf(Wsrc[kx * 128 + n]);
}

// ---------------------------------------------------------------------------
// Kernel 1 (qkv_mega): C[16384x384] = bf16(x) @ Wt^T + bias, x read ONCE.
// [R12 verbatim]
// ---------------------------------------------------------------------------
__global__ __launch_bounds__(512) void qkv_mega(
    const float* __restrict__ x, const short* __restrict__ Wt,
    const float* __restrict__ bq, const float* __restrict__ bk, const float* __restrict__ bv,
    short* __restrict__ qo, short* __restrict__ ko, short* __restrict__ vo)
{
    __shared__ __align__(16) short As[2][64 * 64];    // 16 KB
    __shared__ __align__(16) short Bs[2][384 * 64];   // 96 KB

    const int m0   = blockIdx.x * 64;
    const int tid  = threadIdx.x;
    const int wave = tid >> 6, lane = tid & 63;
    const int quad = lane >> 4, l16 = lane & 15;

    f32x4 acc[4][3];
    for (int i = 0; i < 4; i++)
        for (int j = 0; j < 3; j++) acc[i][j] = (f32x4){0.f, 0.f, 0.f, 0.f};

    const int sr  = lane >> 3;                    // 0..7
    const int sc  = (lane & 7) ^ (sr & 7);
    const int ar  = tid >> 3;                     // 0..63  (A row)
    const int ac8 = tid & 7;                      // A source chunk col
    const int aslot = ar * 8 + (ac8 ^ (ar & 7));  // swizzled A chunk slot

    float4 a0, a1;                                // in-flight A (8 fp32/lane)

#define A_LOAD(kk) {                                                        \
        const float4* s4 = (const float4*)(x + (size_t)(m0 + ar) * 512 + (kk) + ac8 * 8); \
        a0 = s4[0]; a1 = s4[1]; }
#define A_WRITE(buf) {                                                      \
        u32x4 p;                                                            \
        p[0] = cvtpk(a0.x, a0.y); p[1] = cvtpk(a0.z, a0.w);                 \
        p[2] = cvtpk(a1.x, a1.y); p[3] = cvtpk(a1.z, a1.w);                 \
        *(u32x4*)&As[buf][aslot * 8] = p; }
#define B_STAGE(buf, kk)                                                    \
    for (int i = 0; i < 6; i++) {                                           \
        int ins = wave * 6 + i;                   /* 0..47 */               \
        int r = ins * 8 + sr;                     /* 0..383 */              \
        async16(Wt + r * 512 + (kk) + sc * 8, &Bs[buf][ins * 512]);         \
    }

    A_LOAD(0)
    B_STAGE(0, 0)
    A_WRITE(0)
    __syncthreads();                              // lgkm + vmcnt drained

    int cur = 0;
    for (int t = 0; t < 8; t++) {
        if (t < 7) {
            A_LOAD((t + 1) * 64)                  // issue early (T14)
            B_STAGE(cur ^ 1, (t + 1) * 64)
        }

        for (int kc = 0; kc < 2; kc++) {
            bf16x8 af[4], bfr[3];
            int cc = kc * 4 + quad;
            for (int mt = 0; mt < 4; mt++) {
                int R = mt * 16 + l16;            // 0..63
                af[mt] = *(const bf16x8*)&As[cur][(R * 8 + (cc ^ (R & 7))) * 8];
            }
            for (int nf = 0; nf < 3; nf++) {
                int R = wave * 48 + nf * 16 + l16; // 0..383 (output col)
                bfr[nf] = *(const bf16x8*)&Bs[cur][(R * 8 + (cc ^ (R & 7))) * 8];
            }
            for (int mt = 0; mt < 4; mt++)
                for (int nf = 0; nf < 3; nf++)
                    acc[mt][nf] = __builtin_amdgcn_mfma_f32_16x16x32_bf16(
                        af[mt], bfr[nf], acc[mt][nf], 0, 0, 0);
        }
        if (t < 7) { A_WRITE(cur ^ 1) }           // A landed under MFMA
        __syncthreads();
        cur ^= 1;
    }
#undef A_LOAD
#undef A_WRITE
#undef B_STAGE

    const float* const bps[3] = { bq, bk, bv };
    short* const ops[3] = { qo, ko, vo };
    for (int nf = 0; nf < 3; nf++) {
        int colb = wave * 48 + nf * 16;           // frag never straddles mats
        int mat = colb >> 7;
        int lc  = (colb & 127) + l16;
        float bb = bps[mat][lc];
        short* outp = ops[mat];
        for (int mt = 0; mt < 4; mt++) {
            int grow = m0 + mt * 16 + quad * 4;   // C/D row = quad*4+reg
            for (int r = 0; r < 4; r++)
                outp[(size_t)(grow + r) * 128 + lc] = f2bf(acc[mt][nf][r] + bb);
        }
    }
}

// ---------------------------------------------------------------------------
// Kernel 2 (pass 1): l_part[kc][b][row] = per-chunk row sums of exp(S-10).
// 128 q-rows/block, KV tile 32 (LDS 2x8KB -> ~19KB total -> 8 blocks/CU),
// grid (16, 8, 16) = 2048 blocks (8/CU). Double-buffer + setprio.
// Block (0,0,0) zero-inits accum.
// ---------------------------------------------------------------------------
__global__ __launch_bounds__(256) void attn_l(
    const short* __restrict__ q, const short* __restrict__ k,
    float* __restrict__ l_part, float* __restrict__ accum)
{
    __shared__ __align__(16) short ks[2][KTILE * 128];   // swizzled, C=16 (2x8KB)

    const int b  = blockIdx.y;
    const int q0 = blockIdx.x * 128;
    const int lq = blockIdx.z;
    const int c0 = lq * CHUNK;
    const int tid  = threadIdx.x;
    const int wave = tid >> 6, lane = tid & 63;
    const int quad = lane >> 4, l16 = lane & 15;

    if (blockIdx.x == 0 && blockIdx.y == 0 && blockIdx.z == 0) {
        accum[tid] = 0.f; accum[256 + tid] = 0.f;
        accum[512 + tid] = 0.f; accum[768 + tid] = 0.f;
    }

    bf16x8 qf[2][4];
    for (int m = 0; m < 2; m++)
        for (int c = 0; c < 4; c++)
            qf[m][c] = *(const bf16x8*)(q + (b * 2048 + q0 + wave * 32 + m * 16 + l16) * 128
                                          + c * 32 + quad * 8);

    float lsum[2][4] = {{0.f,0.f,0.f,0.f},{0.f,0.f,0.f,0.f}};
    const int krl = lane >> 4;                        // 0..3

// 32 rows x 16 chunks = 512 chunks; 256 threads -> 2 async16 each.
// group ik = 4 rows (64 chunks = 1 wave-call = 1KB).
#define K_STAGE(buf, s0)                                                     \
    for (int i = 0; i < 2; i++) {                                            \
        int ik = wave * 2 + i;                        /* 0..7 */             \
        int kr = ik * 4 + krl;                        /* 0..31 */            \
        int kc8 = (lane & 15) ^ (kr & 15);                                   \
        async16(k + (b * 2048 + (s0) + kr) * 128 + kc8 * 8, &ks[buf][ik * 512]); \
    }

    K_STAGE(0, c0)
    __syncthreads();

    int cur = 0;
    for (int t = 0; t < CHUNK / KTILE; t++) {         // 4 tiles of 32
        if (t < CHUNK / KTILE - 1) { K_STAGE(cur ^ 1, c0 + (t + 1) * KTILE) }

        for (int ct = 0; ct < 2; ct++) {              // 32 kv rows = 2 frags
            f32x4 Sf[2];
            Sf[0] = (f32x4){0.f,0.f,0.f,0.f};
            Sf[1] = (f32x4){0.f,0.f,0.f,0.f};
            int R = ct * 16 + l16;                    // R&15 == l16
            __builtin_amdgcn_s_setprio(1);
            for (int c = 0; c < 4; c++) {
                int cc = c * 4 + quad;
                bf16x8 kb = *(const bf16x8*)&ks[cur][(R * 16 + (cc ^ l16)) * 8];
                for (int m = 0; m < 2; m++)
                    Sf[m] = __builtin_amdgcn_mfma_f32_16x16x32_bf16(
                        qf[m][c], kb, Sf[m], 0, 0, 0);
            }
            __builtin_amdgcn_s_setprio(0);
            for (int m = 0; m < 2; m++)
                for (int r = 0; r < 4; r++)
                    lsum[m][r] += __expf(Sf[m][r] - 10.0f);
        }
        __syncthreads();
        cur ^= 1;
    }

    for (int m = 0; m < 2; m++)
        for (int r = 0; r < 4; r++) {
            float lv = lsum[m][r];
            lv += __shfl_xor(lv, 1);
            lv += __shfl_xor(lv, 2);
            lv += __shfl_xor(lv, 4);
            lv += __shfl_xor(lv, 8);
            if (l16 == 0)
                l_part[(lq * 8 + b) * 2048 + q0 + wave * 32 + m * 16 + quad * 4 + r] = lv;
        }
}

// ---------------------------------------------------------------------------
// Kernel 3 (pass 2): w_part[qt][b][k] = sum over this block's 128 q-rows of
// exp(S-10)/l_total[row]. KV tile 32, grid (16, 8, 16). Plain stores.
// ---------------------------------------------------------------------------
__global__ __launch_bounds__(256) void attn_w(
    const short* __restrict__ q, const short* __restrict__ k,
    const float* __restrict__ l_part, float* __restrict__ w_part)
{
    __shared__ __align__(16) short ks[2][KTILE * 128];   // swizzled (2x8KB)
    __shared__ float wl[4][CHUNK];                       // 4x128 fp32 = 2KB

    const int b  = blockIdx.y;
    const int qt = blockIdx.x;
    const int q0 = qt * 128;
    const int lq = blockIdx.z;
    const int c0 = lq * CHUNK;
    const int tid  = threadIdx.x;
    const int wave = tid >> 6, lane = tid & 63;
    const int quad = lane >> 4, l16 = lane & 15;

    bf16x8 qf[2][4];
    for (int m = 0; m < 2; m++)
        for (int c = 0; c < 4; c++)
            qf[m][c] = *(const bf16x8*)(q + (b * 2048 + q0 + wave * 32 + m * 16 + l16) * 128
                                          + c * 32 + quad * 8);

    float linv[2][4];
    for (int m = 0; m < 2; m++)
        for (int r = 0; r < 4; r++) {
            int row = q0 + wave * 32 + m * 16 + quad * 4 + r;
            float lt = 0.f;
            for (int kc = 0; kc < KC; kc++) lt += l_part[(kc * 8 + b) * 2048 + row];
            linv[m][r] = 1.0f / lt;
        }

    const int krl = lane >> 4;

    K_STAGE(0, c0)
    __syncthreads();

    int cur = 0;
    for (int t = 0; t < CHUNK / KTILE; t++) {
        if (t < CHUNK / KTILE - 1) { K_STAGE(cur ^ 1, c0 + (t + 1) * KTILE) }

        for (int ct = 0; ct < 2; ct++) {
            f32x4 Sf[2];
            Sf[0] = (f32x4){0.f,0.f,0.f,0.f};
            Sf[1] = (f32x4){0.f,0.f,0.f,0.f};
            int R = ct * 16 + l16;
            __builtin_amdgcn_s_setprio(1);
            for (int c = 0; c < 4; c++) {
                int cc = c * 4 + quad;
                bf16x8 kb = *(const bf16x8*)&ks[cur][(R * 16 + (cc ^ l16)) * 8];
                for (int m = 0; m < 2; m++)
                    Sf[m] = __builtin_amdgcn_mfma_f32_16x16x32_bf16(
                        qf[m][c], kb, Sf[m], 0, 0, 0);
            }
            __builtin_amdgcn_s_setprio(0);
            float cs = 0.f;
            for (int m = 0; m < 2; m++)
                for (int r = 0; r < 4; r++)
                    cs += __expf(Sf[m][r] - 10.0f) * linv[m][r];
            cs += __shfl_xor(cs, 16);
            cs += __shfl_xor(cs, 32);
            if (quad == 0) wl[wave][t * KTILE + ct * 16 + l16] = cs;
        }
        __syncthreads();
        cur ^= 1;
    }
#undef K_STAGE

    if (tid < CHUNK) {
        float s = wl[0][tid] + wl[1][tid] + wl[2][tid] + wl[3][tid];
        w_part[(qt * 8 + b) * 2048 + c0 + tid] = s;
    }
}

// ---------------------------------------------------------------------------
// Kernel 4 (wv): accum[b][d] += sum_s w[b][s] * V[b][s][d], V row-major.
// [R12 verbatim]
// ---------------------------------------------------------------------------
__global__ __launch_bounds__(256) void wv(
    const float* __restrict__ w_part, const short* __restrict__ vo,
    float* __restrict__ accum)
{
    __shared__ float wsh[128];
    __shared__ float red[16][129];                 // +1 pad: conflict-free reads
    const int b    = blockIdx.x;
    const int slab = blockIdx.y;                   // 16 slabs of 128 rows
    const int tid  = threadIdx.x;

    if (tid < 128) {
        int s = slab * 128 + tid;
        float wsum = 0.f;
        for (int qt = 0; qt < 16; qt++) wsum += w_part[(qt * 8 + b) * 2048 + s];
        wsh[tid] = wsum;
    }
    __syncthreads();

    const int dgrp = tid & 15, sgrp = tid >> 4;
    const int d0 = dgrp * 8;
    float a[8] = {0.f,0.f,0.f,0.f,0.f,0.f,0.f,0.f};
    for (int i = 0; i < 8; i++) {
        int sl = sgrp * 8 + i;
        bf16x8 v = *(const bf16x8*)(vo + (size_t)(b * 2048 + slab * 128 + sl) * 128 + d0);
        float w = wsh[sl];
        for (int j = 0; j < 8; j++) a[j] += w * bf2f(v[j]);
    }
    for (int j = 0; j < 8; j++) red[sgrp][d0 + j] = a[j];
    __syncthreads();

    if (tid < 128) {
        float s = 0.f;
        for (int g = 0; g < 16; g++) s += red[g][tid];
        atomicAdd(&accum[b * 128 + tid], s);
    }
}

// ---------------------------------------------------------------------------
// Kernel 5: out[b][c] = (accum[b][:]/2048) . Wl[:,c] + bl[c], fp32 out.
// 32 blocks spread the 4MB Wl read (R6 lesson: never 1 block).
// ---------------------------------------------------------------------------
__global__ void final_proj(const float* __restrict__ accum, const float* __restrict__ Wl,
                           const float* __restrict__ bl, float* __restrict__ out)
{
    int id = blockIdx.x * 256 + threadIdx.x;
    if (id >= NB * CC) return;
    int b = id / CC, c = id % CC;
    float s = 0.f;
    for (int d = 0; d < 128; d++)
        s += accum[b * 128 + d] * Wl[d * 1000 + c];
    out[id] = s * (1.0f / 2048.0f) + bl[c];
}

// ---------------------------------------------------------------------------
extern "C" void kernel_launch(void* const* d_in, const int* in_sizes, int n_in,
                              void* d_out, int out_size, void* d_ws, size_t ws_size,
                              hipStream_t stream) {
    const float* x  = (const float*)d_in[0];
    const float* Wq = (const float*)d_in[1];
    const float* bq = (const float*)d_in[2];
    const float* Wk = (const float*)d_in[3];
    const float* bk = (const float*)d_in[4];
    const float* Wv = (const float*)d_in[5];
    const float* bv = (const float*)d_in[6];
    const float* Wl = (const float*)d_in[7];
    const float* bl = (const float*)d_in[8];
    float* out = (float*)d_out;

    char* ws = (char*)d_ws;
    short* qo     = (short*)(ws);                 // 4 MiB
    short* ko     = (short*)(ws + 4194304);       // 4 MiB
    short* vo     = (short*)(ws + 8388608);       // 4 MiB, row-major [b][s][d]
    short* Wt     = (short*)(ws + 12582912);      // 384 KiB ([384][512] bf16)
    float* l_part = (float*)(ws + 12976128);      // 1 MiB (KC*8*2048 fp32)
    float* w_part = (float*)(ws + 14024704);      // 1 MiB (16*8*2048 fp32)
    float* acc    = (float*)(ws + 15073280);      // 4 KiB
    // total ~15 MiB of d_ws

    prep<<<768, 256, 0, stream>>>(Wq, Wk, Wv, Wt);
    qkv_mega<<<256, 512, 0, stream>>>(x, Wt, bq, bk, bv, qo, ko, vo);
    attn_l<<<dim3(16, 8, KC), 256, 0, stream>>>(qo, ko, l_part, acc);
    attn_w<<<dim3(16, 8, KC), 256, 0, stream>>>(qo, ko, l_part, w_part);
    wv<<<dim3(8, 16), 256, 0, stream>>>(w_part, vo, acc);
    final_proj<<<(NB * CC + 255) / 256, 256, 0, stream>>>(acc, Wl, bl, out);
}

// Round 15
// 144.667 us; speedup vs baseline: 1.0328x; 1.0328x over previous
//
#include <hip/hip_runtime.h>
#include <stdint.h>

// B=8, S=2048, F=512, D=128, C=1000. I/O fp32; internal bf16 MFMA, fp32 accum.
// mean-attention: w[k] = sum_s exp(S[s,k]-10)/l[s]; out_sum = w.V row-major.
// R14 post-mortem: attention occupancy attack nulled (+5.5us) -> attn is
// per-wave-latency bound, not wave-count bound. Reverted to R12 attention.
// R15: qkv_mega occupancy fix. R12's Bs=96KB forced 1 block/CU (8 waves).
// BN 384->192, grid (256,2), 256 thr: LDS 64KB -> 2 blocks/CU (16 waves),
// cross-block overlap hides barrier drains. Same BK=64 swizzle, same MFMA
// totals; 2nd x read is L3-served. attn/wv/final = R12 verbatim.
#define NB 8
#define SS 2048
#define FF 512
#define DD 128
#define CC 1000
#define KC 8              // KV split factor
#define CHUNK (SS / KC)   // 256

typedef __attribute__((ext_vector_type(8))) short bf16x8;
typedef __attribute__((ext_vector_type(4))) float f32x4;
typedef __attribute__((ext_vector_type(4))) unsigned int u32x4;

__device__ __forceinline__ short f2bf(float f) {
    uint32_t u;
    __builtin_memcpy(&u, &f, 4);
    u = (u + 0x7fffu + ((u >> 16) & 1u)) >> 16;   // RNE
    return (short)u;
}
__device__ __forceinline__ float bf2f(short h) {
    uint32_t u = ((uint32_t)(uint16_t)h) << 16;
    float f;
    __builtin_memcpy(&f, &u, 4);
    return f;
}
// 2x f32 -> packed bf16x2 (lo=a, hi=b), single HW instr (RNE)
__device__ __forceinline__ uint32_t cvtpk(float a, float b) {
    uint32_t r;
    asm("v_cvt_pk_bf16_f32 %0, %1, %2" : "=v"(r) : "v"(a), "v"(b));
    return r;
}
// async 16B global->LDS; LDS dest = wave-uniform base + lane*16
__device__ __forceinline__ void async16(const void* g, void* l) {
    __builtin_amdgcn_global_load_lds(
        (const __attribute__((address_space(1))) uint32_t*)g,
        (__attribute__((address_space(3))) uint32_t*)l, 16, 0, 0);
}

// ---------------------------------------------------------------------------
// Kernel 0 (prep): transpose+cast W [F][D]f32 x3 -> Wt[384][512] bf16
// (row = global output col: mat*128 + d). grid = 768 blocks.
// ---------------------------------------------------------------------------
__global__ void prep(const float* __restrict__ Wq, const float* __restrict__ Wk,
                     const float* __restrict__ Wv, short* __restrict__ Wt)
{
    int id = blockIdx.x * 256 + threadIdx.x;      // 0..196607
    int w = id >> 16, rem = id & 65535;
    int n = rem >> 9, kx = rem & 511;
    const float* Wsrc = (w == 0) ? Wq : (w == 1) ? Wk : Wv;
    Wt[w * 65536 + n * 512 + kx] = f2bf(Wsrc[kx * 128 + n]);
}

// ---------------------------------------------------------------------------
// Kernel 1 (qkv_mega): C[16384x384] = bf16(x) @ Wt^T + bias.
// R15: BN=192 per block, grid (256 m-tiles, 2 n-blocks), 256 threads
// (4 waves x 3 n-frags x 4 m-frags). LDS 64KB -> 2 blocks/CU.
// A reg-staged (fp32->cvtpk->swizzled LDS, 2 chunks/thread), B via async16.
// T14 split + double buffer. Epilogue: col>>7 selects qo/ko/vo (+bias).
// ---------------------------------------------------------------------------
__global__ __launch_bounds__(256) void qkv_mega(
    const float* __restrict__ x, const short* __restrict__ Wt,
    const float* __restrict__ bq, const float* __restrict__ bk, const float* __restrict__ bv,
    short* __restrict__ qo, short* __restrict__ ko, short* __restrict__ vo)
{
    __shared__ __align__(16) short As[2][64 * 64];    // 16 KB
    __shared__ __align__(16) short Bs[2][192 * 64];   // 48 KB

    const int m0   = blockIdx.x * 64;
    const int n0   = blockIdx.y * 192;
    const int tid  = threadIdx.x;
    const int wave = tid >> 6, lane = tid & 63;
    const int quad = lane >> 4, l16 = lane & 15;

    f32x4 acc[4][3];
    for (int i = 0; i < 4; i++)
        for (int j = 0; j < 3; j++) acc[i][j] = (f32x4){0.f, 0.f, 0.f, 0.f};

    const int sr  = lane >> 3;                    // 0..7
    const int sc  = (lane & 7) ^ (sr & 7);

    // A staging: 64x64 tile = 512 chunks, 256 threads -> 2 chunks each
    const int ar0 = tid >> 3,        ac0 = tid & 7;           // chunk tid
    const int ar1 = (tid + 256) >> 3, ac1 = (tid + 256) & 7;  // chunk tid+256
    const int aslot0 = ar0 * 8 + (ac0 ^ (ar0 & 7));
    const int aslot1 = ar1 * 8 + (ac1 ^ (ar1 & 7));

    float4 a0[2], a1[2];                          // in-flight A (16 fp32)

#define A_LOAD(kk) {                                                        \
        const float4* s4a = (const float4*)(x + (size_t)(m0 + ar0) * 512 + (kk) + ac0 * 8); \
        a0[0] = s4a[0]; a1[0] = s4a[1];                                     \
        const float4* s4b = (const float4*)(x + (size_t)(m0 + ar1) * 512 + (kk) + ac1 * 8); \
        a0[1] = s4b[0]; a1[1] = s4b[1]; }
#define A_WRITE(buf) {                                                      \
        u32x4 p;                                                            \
        p[0] = cvtpk(a0[0].x, a0[0].y); p[1] = cvtpk(a0[0].z, a0[0].w);     \
        p[2] = cvtpk(a1[0].x, a1[0].y); p[3] = cvtpk(a1[0].z, a1[0].w);     \
        *(u32x4*)&As[buf][aslot0 * 8] = p;                                  \
        p[0] = cvtpk(a0[1].x, a0[1].y); p[1] = cvtpk(a0[1].z, a0[1].w);     \
        p[2] = cvtpk(a1[1].x, a1[1].y); p[3] = cvtpk(a1[1].z, a1[1].w);     \
        *(u32x4*)&As[buf][aslot1 * 8] = p; }
#define B_STAGE(buf, kk)                                                    \
    for (int i = 0; i < 6; i++) {                                           \
        int ins = wave * 6 + i;                   /* 0..23 */               \
        int r = ins * 8 + sr;                     /* 0..191 */              \
        async16(Wt + (size_t)(n0 + r) * 512 + (kk) + sc * 8,                \
                &Bs[buf][ins * 512]);                                       \
    }

    A_LOAD(0)
    B_STAGE(0, 0)
    A_WRITE(0)
    __syncthreads();                              // lgkm + vmcnt drained

    int cur = 0;
    for (int t = 0; t < 8; t++) {
        if (t < 7) {
            A_LOAD((t + 1) * 64)                  // issue early (T14)
            B_STAGE(cur ^ 1, (t + 1) * 64)
        }

        for (int kc = 0; kc < 2; kc++) {
            bf16x8 af[4], bfr[3];
            int cc = kc * 4 + quad;
            for (int mt = 0; mt < 4; mt++) {
                int R = mt * 16 + l16;            // 0..63
                af[mt] = *(const bf16x8*)&As[cur][(R * 8 + (cc ^ (R & 7))) * 8];
            }
            for (int nf = 0; nf < 3; nf++) {
                int R = wave * 48 + nf * 16 + l16; // 0..191 (local col)
                bfr[nf] = *(const bf16x8*)&Bs[cur][(R * 8 + (cc ^ (R & 7))) * 8];
            }
            for (int mt = 0; mt < 4; mt++)
                for (int nf = 0; nf < 3; nf++)
                    acc[mt][nf] = __builtin_amdgcn_mfma_f32_16x16x32_bf16(
                        af[mt], bfr[nf], acc[mt][nf], 0, 0, 0);
        }
        if (t < 7) { A_WRITE(cur ^ 1) }           // A landed under MFMA
        __syncthreads();
        cur ^= 1;
    }
#undef A_LOAD
#undef A_WRITE
#undef B_STAGE

    const float* const bps[3] = { bq, bk, bv };
    short* const ops[3] = { qo, ko, vo };
    for (int nf = 0; nf < 3; nf++) {
        int colb = n0 + wave * 48 + nf * 16;      // frag never straddles mats
        int mat = colb >> 7;
        int lc  = (colb & 127) + l16;
        float bb = bps[mat][lc];
        short* outp = ops[mat];
        for (int mt = 0; mt < 4; mt++) {
            int grow = m0 + mt * 16 + quad * 4;   // C/D row = quad*4+reg
            for (int r = 0; r < 4; r++)
                outp[(size_t)(grow + r) * 128 + lc] = f2bf(acc[mt][nf][r] + bb);
        }
    }
}

// ---------------------------------------------------------------------------
// Kernel 2 (pass 1): l_part[kc][b][row] = per-chunk row sums of exp(S-10).
// 128 q-rows/block, KV tile 64, double-buffered K + setprio. Block (0,0,0)
// zero-inits accum. grid = (16, 8, KC).  [R12 verbatim]
// ---------------------------------------------------------------------------
__global__ __launch_bounds__(256) void attn_l(
    const short* __restrict__ q, const short* __restrict__ k,
    float* __restrict__ l_part, float* __restrict__ accum)
{
    __shared__ __align__(16) short ks[2][64 * 128];   // swizzled, C=16

    const int b  = blockIdx.y;
    const int q0 = blockIdx.x * 128;
    const int lq = blockIdx.z;
    const int c0 = lq * CHUNK;
    const int tid  = threadIdx.x;
    const int wave = tid >> 6, lane = tid & 63;
    const int quad = lane >> 4, l16 = lane & 15;

    if (blockIdx.x == 0 && blockIdx.y == 0 && blockIdx.z == 0) {
        accum[tid] = 0.f; accum[256 + tid] = 0.f;
        accum[512 + tid] = 0.f; accum[768 + tid] = 0.f;
    }

    bf16x8 qf[2][4];
    for (int m = 0; m < 2; m++)
        for (int c = 0; c < 4; c++)
            qf[m][c] = *(const bf16x8*)(q + (b * 2048 + q0 + wave * 32 + m * 16 + l16) * 128
                                          + c * 32 + quad * 8);

    float lsum[2][4] = {{0.f,0.f,0.f,0.f},{0.f,0.f,0.f,0.f}};
    const int krl = lane >> 4;                        // 0..3

#define K_STAGE(buf, s0)                                                     \
    for (int i = 0; i < 4; i++) {                                            \
        int ik = wave * 4 + i;                                               \
        int kr = ik * 4 + krl;                                               \
        int kc8 = (lane & 15) ^ (kr & 15);                                   \
        async16(k + (b * 2048 + (s0) + kr) * 128 + kc8 * 8, &ks[buf][ik * 512]); \
    }

    K_STAGE(0, c0)
    __syncthreads();

    int cur = 0;
    for (int t = 0; t < CHUNK / 64; t++) {
        if (t < CHUNK / 64 - 1) { K_STAGE(cur ^ 1, c0 + (t + 1) * 64) }

        for (int ct = 0; ct < 4; ct++) {
            f32x4 Sf[2];
            Sf[0] = (f32x4){0.f,0.f,0.f,0.f};
            Sf[1] = (f32x4){0.f,0.f,0.f,0.f};
            int R = ct * 16 + l16;                    // R&15 == l16
            __builtin_amdgcn_s_setprio(1);
            for (int c = 0; c < 4; c++) {
                int cc = c * 4 + quad;
                bf16x8 kb = *(const bf16x8*)&ks[cur][(R * 16 + (cc ^ l16)) * 8];
                for (int m = 0; m < 2; m++)
                    Sf[m] = __builtin_amdgcn_mfma_f32_16x16x32_bf16(
                        qf[m][c], kb, Sf[m], 0, 0, 0);
            }
            __builtin_amdgcn_s_setprio(0);
            for (int m = 0; m < 2; m++)
                for (int r = 0; r < 4; r++)
                    lsum[m][r] += __expf(Sf[m][r] - 10.0f);
        }
        __syncthreads();
        cur ^= 1;
    }

    for (int m = 0; m < 2; m++)
        for (int r = 0; r < 4; r++) {
            float lv = lsum[m][r];
            lv += __shfl_xor(lv, 1);
            lv += __shfl_xor(lv, 2);
            lv += __shfl_xor(lv, 4);
            lv += __shfl_xor(lv, 8);
            if (l16 == 0)
                l_part[(lq * 8 + b) * 2048 + q0 + wave * 32 + m * 16 + quad * 4 + r] = lv;
        }
}

// ---------------------------------------------------------------------------
// Kernel 3 (pass 2): w_part[qt][b][k] = sum over this block's 128 q-rows of
// exp(S-10)/l_total[row]. Plain stores -> no atomics. grid = (16, 8, KC).
// [R12 verbatim]
// ---------------------------------------------------------------------------
__global__ __launch_bounds__(256) void attn_w(
    const short* __restrict__ q, const short* __restrict__ k,
    const float* __restrict__ l_part, float* __restrict__ w_part)
{
    __shared__ __align__(16) short ks[2][64 * 128];   // swizzled, C=16
    __shared__ float wl[4][256];

    const int b  = blockIdx.y;
    const int qt = blockIdx.x;
    const int q0 = qt * 128;
    const int lq = blockIdx.z;
    const int c0 = lq * CHUNK;
    const int tid  = threadIdx.x;
    const int wave = tid >> 6, lane = tid & 63;
    const int quad = lane >> 4, l16 = lane & 15;

    bf16x8 qf[2][4];
    for (int m = 0; m < 2; m++)
        for (int c = 0; c < 4; c++)
            qf[m][c] = *(const bf16x8*)(q + (b * 2048 + q0 + wave * 32 + m * 16 + l16) * 128
                                          + c * 32 + quad * 8);

    float linv[2][4];
    for (int m = 0; m < 2; m++)
        for (int r = 0; r < 4; r++) {
            int row = q0 + wave * 32 + m * 16 + quad * 4 + r;
            float lt = 0.f;
            for (int kc = 0; kc < KC; kc++) lt += l_part[(kc * 8 + b) * 2048 + row];
            linv[m][r] = 1.0f / lt;
        }

    const int krl = lane >> 4;

    K_STAGE(0, c0)
    __syncthreads();

    int cur = 0;
    for (int t = 0; t < CHUNK / 64; t++) {
        if (t < CHUNK / 64 - 1) { K_STAGE(cur ^ 1, c0 + (t + 1) * 64) }
        int s0 = c0 + t * 64;

        for (int ct = 0; ct < 4; ct++) {
            f32x4 Sf[2];
            Sf[0] = (f32x4){0.f,0.f,0.f,0.f};
            Sf[1] = (f32x4){0.f,0.f,0.f,0.f};
            int R = ct * 16 + l16;
            __builtin_amdgcn_s_setprio(1);
            for (int c = 0; c < 4; c++) {
                int cc = c * 4 + quad;
                bf16x8 kb = *(const bf16x8*)&ks[cur][(R * 16 + (cc ^ l16)) * 8];
                for (int m = 0; m < 2; m++)
                    Sf[m] = __builtin_amdgcn_mfma_f32_16x16x32_bf16(
                        qf[m][c], kb, Sf[m], 0, 0, 0);
            }
            __builtin_amdgcn_s_setprio(0);
            float cs = 0.f;
            for (int m = 0; m < 2; m++)
                for (int r = 0; r < 4; r++)
                    cs += __expf(Sf[m][r] - 10.0f) * linv[m][r];
            cs += __shfl_xor(cs, 16);
            cs += __shfl_xor(cs, 32);
            if (quad == 0) wl[wave][(s0 - c0) + ct * 16 + l16] = cs;
        }
        __syncthreads();
        cur ^= 1;
    }
#undef K_STAGE

    {
        float s = wl[0][tid] + wl[1][tid] + wl[2][tid] + wl[3][tid];
        w_part[(qt * 8 + b) * 2048 + c0 + tid] = s;
    }
}

// ---------------------------------------------------------------------------
// Kernel 4 (wv): accum[b][d] += sum_s w[b][s] * V[b][s][d], V row-major.
// [R12 verbatim]
// ---------------------------------------------------------------------------
__global__ __launch_bounds__(256) void wv(
    const float* __restrict__ w_part, const short* __restrict__ vo,
    float* __restrict__ accum)
{
    __shared__ float wsh[128];
    __shared__ float red[16][129];                 // +1 pad: conflict-free reads
    const int b    = blockIdx.x;
    const int slab = blockIdx.y;                   // 16 slabs of 128 rows
    const int tid  = threadIdx.x;

    if (tid < 128) {
        int s = slab * 128 + tid;
        float wsum = 0.f;
        for (int qt = 0; qt < 16; qt++) wsum += w_part[(qt * 8 + b) * 2048 + s];
        wsh[tid] = wsum;
    }
    __syncthreads();

    const int dgrp = tid & 15, sgrp = tid >> 4;
    const int d0 = dgrp * 8;
    float a[8] = {0.f,0.f,0.f,0.f,0.f,0.f,0.f,0.f};
    for (int i = 0; i < 8; i++) {
        int sl = sgrp * 8 + i;
        bf16x8 v = *(const bf16x8*)(vo + (size_t)(b * 2048 + slab * 128 + sl) * 128 + d0);
        float w = wsh[sl];
        for (int j = 0; j < 8; j++) a[j] += w * bf2f(v[j]);
    }
    for (int j = 0; j < 8; j++) red[sgrp][d0 + j] = a[j];
    __syncthreads();

    if (tid < 128) {
        float s = 0.f;
        for (int g = 0; g < 16; g++) s += red[g][tid];
        atomicAdd(&accum[b * 128 + tid], s);
    }
}

// ---------------------------------------------------------------------------
// Kernel 5: out[b][c] = (accum[b][:]/2048) . Wl[:,c] + bl[c], fp32 out.
// 32 blocks spread the 4MB Wl read (R6 lesson: never 1 block).
// ---------------------------------------------------------------------------
__global__ void final_proj(const float* __restrict__ accum, const float* __restrict__ Wl,
                           const float* __restrict__ bl, float* __restrict__ out)
{
    int id = blockIdx.x * 256 + threadIdx.x;
    if (id >= NB * CC) return;
    int b = id / CC, c = id % CC;
    float s = 0.f;
    for (int d = 0; d < 128; d++)
        s += accum[b * 128 + d] * Wl[d * 1000 + c];
    out[id] = s * (1.0f / 2048.0f) + bl[c];
}

// ---------------------------------------------------------------------------
extern "C" void kernel_launch(void* const* d_in, const int* in_sizes, int n_in,
                              void* d_out, int out_size, void* d_ws, size_t ws_size,
                              hipStream_t stream) {
    const float* x  = (const float*)d_in[0];
    const float* Wq = (const float*)d_in[1];
    const float* bq = (const float*)d_in[2];
    const float* Wk = (const float*)d_in[3];
    const float* bk = (const float*)d_in[4];
    const float* Wv = (const float*)d_in[5];
    const float* bv = (const float*)d_in[6];
    const float* Wl = (const float*)d_in[7];
    const float* bl = (const float*)d_in[8];
    float* out = (float*)d_out;

    char* ws = (char*)d_ws;
    short* qo     = (short*)(ws);                 // 4 MiB
    short* ko     = (short*)(ws + 4194304);       // 4 MiB
    short* vo     = (short*)(ws + 8388608);       // 4 MiB, row-major [b][s][d]
    short* Wt     = (short*)(ws + 12582912);      // 384 KiB ([384][512] bf16)
    float* l_part = (float*)(ws + 12976128);      // 512 KiB (KC*8*2048 fp32)
    float* w_part = (float*)(ws + 13500416);      // 1 MiB (16*8*2048 fp32)
    float* acc    = (float*)(ws + 14548992);      // 4 KiB
    // total ~14 MiB of d_ws

    prep<<<768, 256, 0, stream>>>(Wq, Wk, Wv, Wt);
    qkv_mega<<<dim3(256, 2), 256, 0, stream>>>(x, Wt, bq, bk, bv, qo, ko, vo);
    attn_l<<<dim3(16, 8, KC), 256, 0, stream>>>(qo, ko, l_part, acc);
    attn_w<<<dim3(16, 8, KC), 256, 0, stream>>>(qo, ko, l_part, w_part);
    wv<<<dim3(8, 16), 256, 0, stream>>>(w_part, vo, acc);
    final_proj<<<(NB * CC + 255) / 256, 256, 0, stream>>>(acc, Wl, bl, out);
}